// Round 2
// baseline (130.934 us; speedup 1.0000x reference)
//
#include <hip/hip_runtime.h>

// Reference collapse analysis (verified, absmax 0.0 in round 1):
//   out[b,f,h,w] == 0 unless f==0 and h<2.
//   out[b,0,i,2u+l] = Y_u[i][l] (identical for every b), u in [0,31)
//   Y_u = AT * ( sum_c U[0,c] .* V[c,u] ) * AT^T
//   U[0,c] = G * filters[0,c] * G^T ;  V[c,u] = B^T * x[0,c,0:4,2u:2u+4] * B
//
// Output = (64,64,62,62) fp32 = 3,936,256 float4. Per batch image: 61,504
// float4, of which only the first 31 are nonzero. 61504 % 256 == 64, so a
// batch's special region (31 float4) always lies wholly inside one 256-thread
// block at offset {0,64,128,192}. Exactly 64 special blocks; each redundantly
// computes the 124 floats (no cross-block communication, no second kernel).

static __device__ const float dG[4][3] = {{1.0f, 0.0f, 0.0f},
                                          {0.5f, 0.5f, 1.2f},
                                          {0.5f,-0.5f, 0.5f},
                                          {0.0f, 0.0f, 1.0f}};
static __device__ const float dB[4][4] = {{1.f, 0.f,-1.f, 0.f},
                                          {0.f, 1.f, 1.f, 0.f},
                                          {0.f,-1.f, 1.f, 0.f},
                                          {0.f, 1.f, 0.f,-1.f}};

__global__ __launch_bounds__(256) void winograd_fused(
        const float* __restrict__ x,
        const float* __restrict__ filters,
        float4* __restrict__ out4) {
    const int baseI = blockIdx.x << 8;   // first float4 index of this block
    const int t = threadIdx.x;

    // smallest batch b with start >= baseI; special if its start is in-block
    const int b = (baseI + 61503) / 61504;
    const bool special = (b < 64) && (b * 61504 < baseI + 256);

    __shared__ float sU[64][16];  // U[c][e], e = i*4+l
    __shared__ float sM[31][16];  // sum_c U.*V per tile u
    __shared__ float sY[124];     // final nonzero floats, image order

    if (special) {
        // ---- Phase A: U[c][e] = sum_{j,k} G[i][j] G[l][k] g[c][j][k] ----
        for (int idx = t; idx < 1024; idx += 256) {
            const int c = idx >> 4, e = idx & 15;
            const int i = e >> 2, l = e & 3;
            const float* g = filters + c * 9;
            float s = 0.f;
#pragma unroll
            for (int j = 0; j < 3; ++j)
#pragma unroll
                for (int k = 0; k < 3; ++k)
                    s += dG[i][j] * dG[l][k] * g[j * 3 + k];
            sU[c][e] = s;
        }
        __syncthreads();

        // ---- Phase B: M[u][e] = sum_c U[c][e] * V[c][u][e] ----
        for (int task = t; task < 496; task += 256) {
            const int u = task >> 4, e = task & 15;
            const int i = e >> 2, l = e & 3;
            float wv[4][4];
#pragma unroll
            for (int j = 0; j < 4; ++j)
#pragma unroll
                for (int k = 0; k < 4; ++k)
                    wv[j][k] = dB[j][i] * dB[k][l];
            float acc = 0.f;
            for (int c = 0; c < 64; ++c) {
                const float* xp = x + c * 4096 + 2 * u;
                float v = 0.f;
#pragma unroll
                for (int j = 0; j < 4; ++j)
#pragma unroll
                    for (int k = 0; k < 4; ++k)
                        v += wv[j][k] * xp[j * 64 + k];
                acc += sU[c][e] * v;
            }
            sM[u][e] = acc;
        }
        __syncthreads();

        // ---- Phase C: Y_u = AT * M_u * AT^T, scatter into row layout ----
        if (t < 31) {
            const int u = t;
            const float AT[2][4] = {{1.f, 1.f, 1.f, 0.f},
                                    {0.f, 1.f,-1.f,-1.f}};
            float t3[2][4];
#pragma unroll
            for (int i = 0; i < 2; ++i)
#pragma unroll
                for (int k = 0; k < 4; ++k) {
                    float s = 0.f;
#pragma unroll
                    for (int j = 0; j < 4; ++j) s += AT[i][j] * sM[u][j * 4 + k];
                    t3[i][k] = s;
                }
#pragma unroll
            for (int i = 0; i < 2; ++i)
#pragma unroll
                for (int l = 0; l < 2; ++l) {
                    float s = 0.f;
#pragma unroll
                    for (int k = 0; k < 4; ++k) s += t3[i][k] * AT[l][k];
                    sY[i * 62 + 2 * u + l] = s;
                }
        }
        __syncthreads();
    }

    float4 v = make_float4(0.f, 0.f, 0.f, 0.f);
    if (special) {
        const int rem = (baseI + t) - b * 61504;
        if (rem >= 0 && rem < 31) {
            v.x = sY[4 * rem + 0];
            v.y = sY[4 * rem + 1];
            v.z = sY[4 * rem + 2];
            v.w = sY[4 * rem + 3];
        }
    }
    out4[baseI + t] = v;
}

extern "C" void kernel_launch(void* const* d_in, const int* in_sizes, int n_in,
                              void* d_out, int out_size, void* d_ws, size_t ws_size,
                              hipStream_t stream) {
    const float* x       = (const float*)d_in[0];  // (64,64,64,64)
    const float* filters = (const float*)d_in[1];  // (64,64,3,3)
    float4* out = (float4*)d_out;                  // (64,64,62,62) = 3,936,256 float4

    winograd_fused<<<15376, 256, 0, stream>>>(x, filters, out);
}

// Round 3
// 104.812 us; speedup vs baseline: 1.2492x; 1.2492x over previous
//
#include <hip/hip_runtime.h>

// Reference collapse analysis (verified absmax 0.0 in rounds 1-2):
//   out[b,f,h,w] == 0 unless f==0 and h<2.
//   out[b,0,i,2u+l] = Y_u[i][l] (identical for every batch b), u in [0,31)
//   Y_u = AT * ( sum_c U[0,c] .* V[c,u] ) * AT^T
//   U[0,c] = G * filters[0,c] * G^T ;  V[c,u] = B^T * x[0,c,0:4,2u:2u+4] * B
//
// Structure (round-2 post-mortem: fusing the compute into the fill created a
// 44 us tail on 64 blocks; keep compute separate and let the vendor memset
// do the 63 MB zero-fill at ~6.5 TB/s):
//   1. hipMemsetAsync(out, 0)                — 61,504 KB of stores, ~10 us
//   2. winograd_scatter<<<31, 64>>>          — 124 nonzero floats x 64 batches
//      (7.9 KB of float2 stores), ~2 us

__global__ void winograd_scatter(const float* __restrict__ x,
                                 const float* __restrict__ filters,
                                 float* __restrict__ out) {
    const int u = blockIdx.x;   // tile col, [0, 31)
    const int c = threadIdx.x;  // channel,  [0, 64)

    const float G[4][3]  = {{1.0f, 0.0f, 0.0f},
                            {0.5f, 0.5f, 1.2f},
                            {0.5f,-0.5f, 0.5f},
                            {0.0f, 0.0f, 1.0f}};
    const float Bm[4][4] = {{1.f, 0.f,-1.f, 0.f},
                            {0.f, 1.f, 1.f, 0.f},
                            {0.f,-1.f, 1.f, 0.f},
                            {0.f, 1.f, 0.f,-1.f}};

    // g = filters[0, c]  (3x3)
    float g[3][3];
#pragma unroll
    for (int j = 0; j < 3; ++j)
#pragma unroll
        for (int k = 0; k < 3; ++k)
            g[j][k] = filters[c * 9 + j * 3 + k];

    // U = G g G^T
    float t1[4][3];
#pragma unroll
    for (int i = 0; i < 4; ++i)
#pragma unroll
        for (int k = 0; k < 3; ++k) {
            float s = 0.f;
#pragma unroll
            for (int j = 0; j < 3; ++j) s += G[i][j] * g[j][k];
            t1[i][k] = s;
        }
    float U[4][4];
#pragma unroll
    for (int i = 0; i < 4; ++i)
#pragma unroll
        for (int l = 0; l < 4; ++l) {
            float s = 0.f;
#pragma unroll
            for (int k = 0; k < 3; ++k) s += t1[i][k] * G[l][k];
            U[i][l] = s;
        }

    // d = x[0, c, 0:4, 2u : 2u+4]
    float d[4][4];
#pragma unroll
    for (int j = 0; j < 4; ++j)
#pragma unroll
        for (int k = 0; k < 4; ++k)
            d[j][k] = x[c * 4096 + j * 64 + 2 * u + k];

    // V = B^T d B
    float t2[4][4];
#pragma unroll
    for (int i = 0; i < 4; ++i)
#pragma unroll
        for (int k = 0; k < 4; ++k) {
            float s = 0.f;
#pragma unroll
            for (int j = 0; j < 4; ++j) s += Bm[j][i] * d[j][k];
            t2[i][k] = s;
        }
    float V[4][4];
#pragma unroll
    for (int i = 0; i < 4; ++i)
#pragma unroll
        for (int l = 0; l < 4; ++l) {
            float s = 0.f;
#pragma unroll
            for (int k = 0; k < 4; ++k) s += t2[i][k] * Bm[k][l];
            V[i][l] = s;
        }

    // elementwise product, reduce over c across the block (64 lanes)
    __shared__ float red[16][64];
#pragma unroll
    for (int i = 0; i < 4; ++i)
#pragma unroll
        for (int l = 0; l < 4; ++l)
            red[i * 4 + l][c] = U[i][l] * V[i][l];
    __syncthreads();

    __shared__ float M[16];
    if (c < 16) {
        float s = 0.f;
        for (int t = 0; t < 64; ++t) s += red[c][t];
        M[c] = s;
    }
    __syncthreads();

    // Y = AT * M * AT^T  (2x2), broadcast via LDS
    __shared__ float sY[4];
    if (c == 0) {
        const float AT[2][4] = {{1.f, 1.f, 1.f, 0.f},
                                {0.f, 1.f,-1.f,-1.f}};
        float t3[2][4];
#pragma unroll
        for (int i = 0; i < 2; ++i)
#pragma unroll
            for (int k = 0; k < 4; ++k) {
                float s = 0.f;
#pragma unroll
                for (int j = 0; j < 4; ++j) s += AT[i][j] * M[j * 4 + k];
                t3[i][k] = s;
            }
#pragma unroll
        for (int i = 0; i < 2; ++i)
#pragma unroll
            for (int l = 0; l < 2; ++l) {
                float s = 0.f;
#pragma unroll
                for (int k = 0; k < 4; ++k) s += t3[i][k] * AT[l][k];
                sY[i * 2 + l] = s;
            }
    }
    __syncthreads();

    // lane c writes batch b=c: rows h=0,1 at w = 2u, 2u+1 (8B-aligned pairs)
    const float2 r0 = make_float2(sY[0], sY[1]);
    const float2 r1 = make_float2(sY[2], sY[3]);
    float* base = out + (size_t)c * 246016 + 2 * u;  // b*64*62*62, f=0
    *(float2*)(base)      = r0;   // h=0
    *(float2*)(base + 62) = r1;   // h=1
}

extern "C" void kernel_launch(void* const* d_in, const int* in_sizes, int n_in,
                              void* d_out, int out_size, void* d_ws, size_t ws_size,
                              hipStream_t stream) {
    const float* x       = (const float*)d_in[0];  // (64,64,64,64)
    const float* filters = (const float*)d_in[1];  // (64,64,3,3)
    float* out = (float*)d_out;                    // (64,64,62,62) fp32

    // 63 MB zero-fill via the vendor fill path (~6.5 TB/s), then scatter the
    // 124 x 64 nonzero floats on top (same stream => ordered).
    hipMemsetAsync(d_out, 0, (size_t)out_size * sizeof(float), stream);
    winograd_scatter<<<31, 64, 0, stream>>>(x, filters, out);
}